// Round 6
// baseline (330.591 us; speedup 1.0000x reference)
//
#include <hip/hip_runtime.h>

#define DIM    1024
#define BATCH  8
#define SEQ    2048
#define NBLK   1024
#define NTHR   256
#define CHUNKS 128
#define ROWS   (SEQ / CHUNKS)   // 16 rows per phase-1 chunk
#define LN_EPS 1e-5f

typedef float v4 __attribute__((ext_vector_type(4)));

// ---------------------------------------------------------------------------
// Lightweight one-shot grid barrier (state zeroed by hipMemsetAsync per call).
// Arrive: agent-scope RELEASE fetch_add  -> cross-XCD publish of this block's
//         prior stores. Wait: leader spins on RELAXED agent load, then one
//         agent ACQUIRE fence so stale L1/L2 lines are dropped before reading
//         other blocks' data. flag goes 0->1 exactly once per call: monotone,
//         no reset race, no pulse-miss.
// ---------------------------------------------------------------------------
__device__ __forceinline__ void gbar(unsigned* cnt, unsigned* flag) {
  __syncthreads();
  if (threadIdx.x == 0) {
    unsigned prev = __hip_atomic_fetch_add(cnt, 1u, __ATOMIC_RELEASE,
                                           __HIP_MEMORY_SCOPE_AGENT);
    if (prev == NBLK - 1) {
      __hip_atomic_store(flag, 1u, __ATOMIC_RELEASE,
                         __HIP_MEMORY_SCOPE_AGENT);
    } else {
      while (__hip_atomic_load(flag, __ATOMIC_RELAXED,
                               __HIP_MEMORY_SCOPE_AGENT) == 0u)
        __builtin_amdgcn_s_sleep(8);
    }
    __builtin_amdgcn_fence(__ATOMIC_ACQUIRE, "agent");
  }
  __syncthreads();
}

// ---------------------------------------------------------------------------
// Fused kernel, 5 phases / 4 custom barriers:
//  P1 : partial column sums of x over s        (reads all of x -> fills L3)
//  P2a: finish column sum -> xsum[b,e]
//  P2b: vsum = xsum @ Wv^T
//  P2c: z    = vsum @ Wfc^T + b_fc
//  P3 : out  = LN(x + z) * gamma + beta        (x re-read: L3 hit)
// ---------------------------------------------------------------------------
__global__ __launch_bounds__(NTHR, 6) void k_fused(
    const float* __restrict__ x, const float* __restrict__ w_v,
    const float* __restrict__ w_fc, const float* __restrict__ b_fc,
    const float* __restrict__ gamma, const float* __restrict__ beta,
    float* __restrict__ out, unsigned* __restrict__ bar,
    float* __restrict__ dat) {
  const int blk = blockIdx.x, t = threadIdx.x;
  const int wv = t >> 6, lane = t & 63;

  float* partial = dat;                                  // CHUNKS*B*D floats
  float* xsum = partial + (size_t)CHUNKS * BATCH * DIM;  // B*D
  float* vsum = xsum + (size_t)BATCH * DIM;              // B*D
  float* z    = vsum + (size_t)BATCH * DIM;              // B*D

  // -------- Phase 1: partial col-sums (1024 blocks = 8b x 128c) --------
  {
    int b = blk >> 7;
    int c = blk & (CHUNKS - 1);
    const v4* base =
        (const v4*)(x + ((size_t)b * SEQ + (size_t)c * ROWS) * DIM) + t;
    v4 a0 = {0.f, 0.f, 0.f, 0.f}, a1 = {0.f, 0.f, 0.f, 0.f};
#pragma unroll
    for (int s = 0; s < ROWS; s += 2) {
      a0 += base[(size_t)s * (DIM / 4)];
      a1 += base[(size_t)(s + 1) * (DIM / 4)];
    }
    ((v4*)partial)[((size_t)c * BATCH + b) * (DIM / 4) + t] = a0 + a1;
  }
  gbar(bar + 0, bar + 1);

  // -------- Phase 2a: finish col-sum (2 v4-elems per block) --------
  {
    int e2 = blk * 2 + (t >> 7);   // v4 index over B*D/4 = 2048
    int ch = t & 127;              // chunk id this thread reduces
    int b  = e2 >> 8;              // D/4 = 256
    int e4 = e2 & 255;
    v4 acc = ((const v4*)partial)[((size_t)ch * BATCH + b) * 256 + e4];
#pragma unroll
    for (int m = 32; m; m >>= 1) {
      acc.x += __shfl_xor(acc.x, m, 64);
      acc.y += __shfl_xor(acc.y, m, 64);
      acc.z += __shfl_xor(acc.z, m, 64);
      acc.w += __shfl_xor(acc.w, m, 64);
    }
    __shared__ v4 red[4];
    if (lane == 0) red[wv] = acc;
    __syncthreads();
    if ((t & 127) == 0) {
      v4 r = red[wv] + red[wv + 1];
      ((v4*)xsum)[e2] = r;
    }
  }
  gbar(bar + 2, bar + 3);

  // -------- Phase 2b: vsum = xsum @ Wv^T (4096 waves x 2 outputs) --------
  {
    int w = blk * 4 + wv;
#pragma unroll
    for (int r = 0; r < 2; ++r) {
      int o = w * 2 + r;  // 0..8191
      int b = o >> 10, d = o & (DIM - 1);
      const v4* in4 = (const v4*)(xsum + (size_t)b * DIM);
      const v4* w4  = (const v4*)(w_v + (size_t)d * DIM);
      float acc = 0.f;
#pragma unroll
      for (int j = 0; j < 4; ++j) {
        v4 a = w4[lane + 64 * j], i = in4[lane + 64 * j];
        acc += a.x * i.x + a.y * i.y + a.z * i.z + a.w * i.w;
      }
#pragma unroll
      for (int m = 32; m; m >>= 1) acc += __shfl_xor(acc, m, 64);
      if (lane == 0) vsum[o] = acc;
    }
  }
  gbar(bar + 4, bar + 5);

  // -------- Phase 2c: z = vsum @ Wfc^T + b_fc --------
  {
    int w = blk * 4 + wv;
#pragma unroll
    for (int r = 0; r < 2; ++r) {
      int o = w * 2 + r;
      int b = o >> 10, d = o & (DIM - 1);
      const v4* in4 = (const v4*)(vsum + (size_t)b * DIM);
      const v4* w4  = (const v4*)(w_fc + (size_t)d * DIM);
      float acc = 0.f;
#pragma unroll
      for (int j = 0; j < 4; ++j) {
        v4 a = w4[lane + 64 * j], i = in4[lane + 64 * j];
        acc += a.x * i.x + a.y * i.y + a.z * i.z + a.w * i.w;
      }
#pragma unroll
      for (int m = 32; m; m >>= 1) acc += __shfl_xor(acc, m, 64);
      if (lane == 0) z[o] = acc + b_fc[d];
    }
  }
  gbar(bar + 6, bar + 7);

  // -------- Phase 3: out = LN(x+z)*gamma + beta (4 rows/wave) --------
  {
    int gw = blk * 4 + wv;  // 0..4095
#pragma unroll 1
    for (int r = 0; r < 4; ++r) {
      int row = gw + r * 4096;  // consecutive waves -> consecutive rows
      int b = row >> 11;        // SEQ = 2048
      const v4* xr = (const v4*)(x + (size_t)row * DIM);
      const v4* zr = (const v4*)(z + (size_t)b * DIM);
      v4 h[4];
      float sum = 0.f, ss = 0.f;
#pragma unroll
      for (int j = 0; j < 4; ++j) {
        v4 hv = xr[lane + 64 * j] + zr[lane + 64 * j];
        h[j] = hv;
        sum += hv.x + hv.y + hv.z + hv.w;
        ss  += hv.x * hv.x + hv.y * hv.y + hv.z * hv.z + hv.w * hv.w;
      }
#pragma unroll
      for (int m = 32; m; m >>= 1) {
        sum += __shfl_xor(sum, m, 64);
        ss  += __shfl_xor(ss,  m, 64);
      }
      const float inv = 1.0f / (float)DIM;
      float mu = sum * inv;
      float rs = rsqrtf(ss * inv - mu * mu + LN_EPS);

      v4* outr = (v4*)out + (size_t)row * (DIM / 4);
#pragma unroll
      for (int j = 0; j < 4; ++j) {
        v4 g  = ((const v4*)gamma)[lane + 64 * j];
        v4 be = ((const v4*)beta)[lane + 64 * j];
        outr[lane + 64 * j] = (h[j] - mu) * rs * g + be;
      }
    }
  }
}

// ------------------------- fallback (multi-kernel, proven R1 path) ---------
__global__ __launch_bounds__(256) void k_partial_colsum(
    const float* __restrict__ x, float* __restrict__ partial) {
  int c = blockIdx.x, b = blockIdx.y, t = threadIdx.x;
  const v4* base =
      (const v4*)(x + ((size_t)b * SEQ + (size_t)c * ROWS) * DIM) + t;
  v4 a0 = {0.f, 0.f, 0.f, 0.f}, a1 = {0.f, 0.f, 0.f, 0.f};
#pragma unroll
  for (int s = 0; s < ROWS; s += 2) {
    a0 += base[(size_t)s * (DIM / 4)];
    a1 += base[(size_t)(s + 1) * (DIM / 4)];
  }
  ((v4*)partial)[((size_t)c * BATCH + b) * (DIM / 4) + t] = a0 + a1;
}

__global__ __launch_bounds__(256) void k_finish_colsum(
    const float* __restrict__ partial, float* __restrict__ xsum) {
  int i4 = blockIdx.x * 256 + threadIdx.x;
  const v4* p = (const v4*)partial;
  v4 acc = {0.f, 0.f, 0.f, 0.f};
#pragma unroll 8
  for (int c = 0; c < CHUNKS; ++c) acc += p[(size_t)c * BATCH * (DIM / 4) + i4];
  ((v4*)xsum)[i4] = acc;
}

__global__ __launch_bounds__(256) void k_gemv(
    const float* __restrict__ vin, const float* __restrict__ W,
    const float* __restrict__ bias, float* __restrict__ vout) {
  int wave = threadIdx.x >> 6, lane = threadIdx.x & 63;
  int o = blockIdx.x * 4 + wave;
  int b = o >> 10, d = o & (DIM - 1);
  const v4* in4 = (const v4*)(vin + (size_t)b * DIM);
  const v4* w4  = (const v4*)(W + (size_t)d * DIM);
  float acc = 0.f;
#pragma unroll
  for (int j = 0; j < 4; ++j) {
    v4 w = w4[lane + 64 * j], i = in4[lane + 64 * j];
    acc += w.x * i.x + w.y * i.y + w.z * i.z + w.w * i.w;
  }
#pragma unroll
  for (int off = 32; off; off >>= 1) acc += __shfl_xor(acc, off, 64);
  if (lane == 0) {
    float r = acc;
    if (bias) r += bias[d];
    vout[o] = r;
  }
}

__global__ __launch_bounds__(256) void k_residual_ln(
    const float* __restrict__ x, const float* __restrict__ z,
    const float* __restrict__ gamma, const float* __restrict__ beta,
    float* __restrict__ out) {
  int wave = threadIdx.x >> 6, lane = threadIdx.x & 63;
  int row = blockIdx.x * 4 + wave;
  int b   = row >> 11;
  const v4* xr = (const v4*)(x + (size_t)row * DIM);
  const v4* zr = (const v4*)(z + (size_t)b * DIM);
  v4 h[4];
  float sum = 0.f, ss = 0.f;
#pragma unroll
  for (int j = 0; j < 4; ++j) {
    v4 hv = xr[lane + 64 * j] + zr[lane + 64 * j];
    h[j] = hv;
    sum += hv.x + hv.y + hv.z + hv.w;
    ss  += hv.x * hv.x + hv.y * hv.y + hv.z * hv.z + hv.w * hv.w;
  }
#pragma unroll
  for (int m = 32; m; m >>= 1) {
    sum += __shfl_xor(sum, m, 64);
    ss  += __shfl_xor(ss,  m, 64);
  }
  const float inv = 1.0f / (float)DIM;
  float mu = sum * inv;
  float rs = rsqrtf(ss * inv - mu * mu + LN_EPS);
  v4* outr = (v4*)out + (size_t)row * (DIM / 4);
#pragma unroll
  for (int j = 0; j < 4; ++j) {
    v4 g  = ((const v4*)gamma)[lane + 64 * j];
    v4 be = ((const v4*)beta)[lane + 64 * j];
    outr[lane + 64 * j] = (h[j] - mu) * rs * g + be;
  }
}

extern "C" void kernel_launch(void* const* d_in, const int* in_sizes, int n_in,
                              void* d_out, int out_size, void* d_ws, size_t ws_size,
                              hipStream_t stream) {
  const float* x     = (const float*)d_in[0];   // [B, S, D]
  const float* w_qkv = (const float*)d_in[1];   // [3D, D]
  const float* w_fc  = (const float*)d_in[2];   // [D, D]
  const float* b_fc  = (const float*)d_in[3];   // [D]
  const float* gamma = (const float*)d_in[4];   // [D]
  const float* beta  = (const float*)d_in[5];   // [D]
  float* out = (float*)d_out;

  unsigned* bar = (unsigned*)d_ws;            // 8 uints (4 barriers)
  float* dat = (float*)((char*)d_ws + 256);   // data area

  const float* w_v = w_qkv + (size_t)2 * DIM * DIM;  // rows [2D,3D) of w_qkv

  // Zero barrier state every call (ws is poisoned 0xAA; graph-capture-legal).
  (void)hipMemsetAsync(bar, 0, 256, stream);

  void* args[] = {(void*)&x,     (void*)&w_v,  (void*)&w_fc, (void*)&b_fc,
                  (void*)&gamma, (void*)&beta, (void*)&out,  (void*)&bar,
                  (void*)&dat};
  hipError_t err = hipLaunchCooperativeKernel((void*)k_fused, dim3(NBLK),
                                              dim3(NTHR), args, 0, stream);
  if (err != hipSuccess) {
    // Fallback: proven multi-kernel path.
    float* partial = dat;
    float* xsum    = partial + (size_t)CHUNKS * BATCH * DIM;
    float* vsum    = xsum + (size_t)BATCH * DIM;
    float* z       = vsum + (size_t)BATCH * DIM;
    hipLaunchKernelGGL(k_partial_colsum, dim3(CHUNKS, BATCH), dim3(256), 0,
                       stream, x, partial);
    hipLaunchKernelGGL(k_finish_colsum, dim3(BATCH * DIM / 4 / 256), dim3(256),
                       0, stream, partial, xsum);
    hipLaunchKernelGGL(k_gemv, dim3(BATCH * DIM / 4), dim3(256), 0, stream,
                       xsum, w_v, (const float*)nullptr, vsum);
    hipLaunchKernelGGL(k_gemv, dim3(BATCH * DIM / 4), dim3(256), 0, stream,
                       vsum, w_fc, b_fc, z);
    hipLaunchKernelGGL(k_residual_ln, dim3(BATCH * SEQ / 4), dim3(256), 0,
                       stream, x, z, gamma, beta, out);
  }
}

// Round 7
// 55.972 us; speedup vs baseline: 5.9063x; 5.9063x over previous
//
#include <hip/hip_runtime.h>

#define DIM    1024
#define BATCH  8
#define SEQ    2048
#define CHUNKS 128
#define ROWS   (SEQ / CHUNKS)   // 16 rows per K1 block
#define LN_EPS 1e-5f

typedef float v4 __attribute__((ext_vector_type(4)));

__device__ __forceinline__ float dot4(v4 a, v4 b) {
  return a.x * b.x + a.y * b.y + a.z * b.z + a.w * b.w;
}

__device__ __forceinline__ float wred(float a) {
#pragma unroll
  for (int m = 32; m; m >>= 1) a += __shfl_xor(a, m, 64);
  return a;
}

// ---------------------------------------------------------------------------
// K1: partial column sums of x over s. grid 1024 (8b x 128c), block 256.
// partial[c][b][e] = sum_{s in chunk c} x[b,s,e]
// ---------------------------------------------------------------------------
__global__ __launch_bounds__(256, 4) void k_partial_colsum(
    const float* __restrict__ x, float* __restrict__ partial) {
  const int blk = blockIdx.x;
  const int b = blk >> 7, c = blk & (CHUNKS - 1), t = threadIdx.x;
  const v4* base = (const v4*)x + ((size_t)(b * SEQ + c * ROWS) << 8) + t;
  v4 a0 = {0.f, 0.f, 0.f, 0.f}, a1 = {0.f, 0.f, 0.f, 0.f};
#pragma unroll
  for (int s = 0; s < ROWS; s += 2) {
    a0 += base[(size_t)s << 8];
    a1 += base[(size_t)(s + 1) << 8];
  }
  ((v4*)partial)[((size_t)(c * BATCH + b) << 8) + t] = a0 + a1;
}

// ---------------------------------------------------------------------------
// K2a: finish colsum (per-block redundant, cheap: 512 KB from L2/L3) then
//      vsum[b, sl*128 .. sl*128+127] = xsum_b @ Wv^T slice.
// grid 64 (8b x 8 slices), block 1024 (16 waves, 8 rows each).
// ---------------------------------------------------------------------------
__global__ __launch_bounds__(1024) void k_gemv1(
    const float* __restrict__ partial, const float* __restrict__ w_v,
    float* __restrict__ vsum) {
  __shared__ v4 ps[4][256];
  __shared__ float xs[DIM];
  const int b = blockIdx.x >> 3, sl = blockIdx.x & 7;
  const int t = threadIdx.x, wv = t >> 6, lane = t & 63;
  {
    const int e4 = t & 255, q = t >> 8;
    const v4* p = (const v4*)partial + ((size_t)b << 8) + e4;
    v4 acc = {0.f, 0.f, 0.f, 0.f};
#pragma unroll 8
    for (int k = 0; k < 32; ++k)
      acc += p[(size_t)(q + 4 * k) * (BATCH * 256)];
    ps[q][e4] = acc;
  }
  __syncthreads();
  if (t < 256) ((v4*)xs)[t] = ps[0][t] + ps[1][t] + ps[2][t] + ps[3][t];
  __syncthreads();

  v4 xf[4];
#pragma unroll
  for (int j = 0; j < 4; ++j) xf[j] = ((const v4*)xs)[lane + 64 * j];

  const int d0 = sl * 128 + wv * 8;
#pragma unroll
  for (int g = 0; g < 2; ++g) {
    const int d = d0 + g * 4;
    const v4* r0 = (const v4*)w_v + ((size_t)(d + 0) << 8);
    const v4* r1 = (const v4*)w_v + ((size_t)(d + 1) << 8);
    const v4* r2 = (const v4*)w_v + ((size_t)(d + 2) << 8);
    const v4* r3 = (const v4*)w_v + ((size_t)(d + 3) << 8);
    v4 w0[4], w1[4], w2[4], w3[4];
#pragma unroll
    for (int j = 0; j < 4; ++j) {
      w0[j] = r0[lane + 64 * j];
      w1[j] = r1[lane + 64 * j];
      w2[j] = r2[lane + 64 * j];
      w3[j] = r3[lane + 64 * j];
    }
    float a0 = 0.f, a1 = 0.f, a2 = 0.f, a3 = 0.f;
#pragma unroll
    for (int j = 0; j < 4; ++j) {
      a0 += dot4(w0[j], xf[j]);
      a1 += dot4(w1[j], xf[j]);
      a2 += dot4(w2[j], xf[j]);
      a3 += dot4(w3[j], xf[j]);
    }
    a0 = wred(a0); a1 = wred(a1); a2 = wred(a2); a3 = wred(a3);
    if (lane == 0) {
      float* vp = vsum + ((size_t)b << 10) + d;
      vp[0] = a0; vp[1] = a1; vp[2] = a2; vp[3] = a3;
    }
  }
}

// ---------------------------------------------------------------------------
// K2b: z[b, sl*128 ..] = vsum_b @ Wfc^T slice + b_fc. grid 64, block 1024.
// ---------------------------------------------------------------------------
__global__ __launch_bounds__(1024) void k_gemv2(
    const float* __restrict__ vsum, const float* __restrict__ w_fc,
    const float* __restrict__ b_fc, float* __restrict__ z) {
  __shared__ float vs[DIM];
  const int b = blockIdx.x >> 3, sl = blockIdx.x & 7;
  const int t = threadIdx.x, wv = t >> 6, lane = t & 63;
  if (t < 256) ((v4*)vs)[t] = ((const v4*)vsum)[((size_t)b << 8) + t];
  __syncthreads();

  v4 vf[4];
#pragma unroll
  for (int j = 0; j < 4; ++j) vf[j] = ((const v4*)vs)[lane + 64 * j];

  const int d0 = sl * 128 + wv * 8;
#pragma unroll
  for (int g = 0; g < 2; ++g) {
    const int d = d0 + g * 4;
    const v4* r0 = (const v4*)w_fc + ((size_t)(d + 0) << 8);
    const v4* r1 = (const v4*)w_fc + ((size_t)(d + 1) << 8);
    const v4* r2 = (const v4*)w_fc + ((size_t)(d + 2) << 8);
    const v4* r3 = (const v4*)w_fc + ((size_t)(d + 3) << 8);
    v4 w0[4], w1[4], w2[4], w3[4];
#pragma unroll
    for (int j = 0; j < 4; ++j) {
      w0[j] = r0[lane + 64 * j];
      w1[j] = r1[lane + 64 * j];
      w2[j] = r2[lane + 64 * j];
      w3[j] = r3[lane + 64 * j];
    }
    float a0 = 0.f, a1 = 0.f, a2 = 0.f, a3 = 0.f;
#pragma unroll
    for (int j = 0; j < 4; ++j) {
      a0 += dot4(w0[j], vf[j]);
      a1 += dot4(w1[j], vf[j]);
      a2 += dot4(w2[j], vf[j]);
      a3 += dot4(w3[j], vf[j]);
    }
    a0 = wred(a0); a1 = wred(a1); a2 = wred(a2); a3 = wred(a3);
    if (lane == 0) {
      float* zp = z + ((size_t)b << 10) + d;
      zp[0] = a0 + b_fc[d];
      zp[1] = a1 + b_fc[d + 1];
      zp[2] = a2 + b_fc[d + 2];
      zp[3] = a3 + b_fc[d + 3];
    }
  }
}

// ---------------------------------------------------------------------------
// K3: out[row,:] = LN(x[row,:] + z[b,:]) * gamma + beta.
// grid 1024 (16 rows/block), block 256 (4 waves, 4 rows each).
// z/gamma/beta hoisted to per-lane register fragments outside the row loop.
// ---------------------------------------------------------------------------
__global__ __launch_bounds__(256, 4) void k_residual_ln(
    const float* __restrict__ x, const float* __restrict__ z,
    const float* __restrict__ gamma, const float* __restrict__ beta,
    float* __restrict__ out) {
  __shared__ float zl[DIM];
  const int blk = blockIdx.x, t = threadIdx.x;
  const int wv = t >> 6, lane = t & 63;
  const int b = blk >> 7;   // 128 blocks per batch

  ((v4*)zl)[t] = ((const v4*)z)[((size_t)b << 8) + t];
  __syncthreads();

  v4 zf[4], gf[4], bf[4];
#pragma unroll
  for (int j = 0; j < 4; ++j) {
    zf[j] = ((const v4*)zl)[lane + 64 * j];
    gf[j] = ((const v4*)gamma)[lane + 64 * j];
    bf[j] = ((const v4*)beta)[lane + 64 * j];
  }

#pragma unroll 1
  for (int r = 0; r < 4; ++r) {
    const int row = (blk << 4) + (wv << 2) + r;
    const v4* xr = (const v4*)x + ((size_t)row << 8);
    v4 h[4];
    float sum = 0.f, ss = 0.f;
#pragma unroll
    for (int j = 0; j < 4; ++j) {
      v4 hv = xr[lane + 64 * j] + zf[j];
      h[j] = hv;
      sum += hv.x + hv.y + hv.z + hv.w;
      ss  += hv.x * hv.x + hv.y * hv.y + hv.z * hv.z + hv.w * hv.w;
    }
#pragma unroll
    for (int m = 32; m; m >>= 1) {
      sum += __shfl_xor(sum, m, 64);
      ss  += __shfl_xor(ss,  m, 64);
    }
    const float inv = 1.0f / (float)DIM;
    const float mu = sum * inv;
    const float rs = rsqrtf(ss * inv - mu * mu + LN_EPS);

    v4* outr = (v4*)out + ((size_t)row << 8);
#pragma unroll
    for (int j = 0; j < 4; ++j)
      outr[lane + 64 * j] = (h[j] - mu) * rs * gf[j] + bf[j];
  }
}

extern "C" void kernel_launch(void* const* d_in, const int* in_sizes, int n_in,
                              void* d_out, int out_size, void* d_ws, size_t ws_size,
                              hipStream_t stream) {
  const float* x     = (const float*)d_in[0];   // [B, S, D]
  const float* w_qkv = (const float*)d_in[1];   // [3D, D]
  const float* w_fc  = (const float*)d_in[2];   // [D, D]
  const float* b_fc  = (const float*)d_in[3];   // [D]
  const float* gamma = (const float*)d_in[4];   // [D]
  const float* beta  = (const float*)d_in[5];   // [D]
  float* out = (float*)d_out;

  // workspace layout (floats)
  float* partial = (float*)d_ws;                             // CHUNKS*B*D
  float* vsum    = partial + (size_t)CHUNKS * BATCH * DIM;   // B*D
  float* z       = vsum + (size_t)BATCH * DIM;               // B*D

  const float* w_v = w_qkv + (size_t)2 * DIM * DIM;  // rows [2D,3D) of w_qkv

  hipLaunchKernelGGL(k_partial_colsum, dim3(BATCH * CHUNKS), dim3(256), 0,
                     stream, x, partial);
  hipLaunchKernelGGL(k_gemv1, dim3(64), dim3(1024), 0, stream,
                     partial, w_v, vsum);
  hipLaunchKernelGGL(k_gemv2, dim3(64), dim3(1024), 0, stream,
                     vsum, w_fc, b_fc, z);
  hipLaunchKernelGGL(k_residual_ln, dim3(BATCH * SEQ / 16), dim3(256), 0,
                     stream, x, z, gamma, beta, out);
}

// Round 8
// 47.145 us; speedup vs baseline: 7.0122x; 1.1872x over previous
//
#include <hip/hip_runtime.h>

#define DIM    1024
#define BATCH  8
#define SEQ    2048
#define CHUNKS 64
#define ROWS   (SEQ / CHUNKS)   // 32 rows per K1 block
#define LN_EPS 1e-5f

typedef float v4 __attribute__((ext_vector_type(4)));

__device__ __forceinline__ float dot4(v4 a, v4 b) {
  return a.x * b.x + a.y * b.y + a.z * b.z + a.w * b.w;
}

// ---------------------------------------------------------------------------
// K1: partial column sums of x over s. grid 512 (8b x 64c), block 256.
// Dual accumulators: two independent dep chains (f32 adds can't reassociate).
// partial[c][b][e] = sum_{s in chunk c} x[b,s,e]
// ---------------------------------------------------------------------------
__global__ __launch_bounds__(256, 4) void k_partial_colsum(
    const float* __restrict__ x, float* __restrict__ partial) {
  const int blk = blockIdx.x;
  const int b = blk >> 6, c = blk & (CHUNKS - 1), t = threadIdx.x;
  const v4* base = (const v4*)x + ((size_t)(b * SEQ + c * ROWS) << 8) + t;
  v4 a0 = {0.f, 0.f, 0.f, 0.f}, a1 = {0.f, 0.f, 0.f, 0.f};
#pragma unroll
  for (int s = 0; s < ROWS; s += 2) {
    a0 += base[(size_t)s << 8];
    a1 += base[(size_t)(s + 1) << 8];
  }
  ((v4*)partial)[((size_t)(c * BATCH + b) << 8) + t] = a0 + a1;
}

// ---------------------------------------------------------------------------
// K2: finish column sum. grid 64, block 256.
// Thread (v4loc = t>>3, grp = t&7): sums chunks {grp, grp+8, ...} (8 loads,
// all independent / in flight), then 8-lane shfl_xor reduce. High MLP vs
// R1's 8-block serial version.
// ---------------------------------------------------------------------------
__global__ __launch_bounds__(256) void k_finish_colsum(
    const float* __restrict__ partial, float* __restrict__ xsum) {
  const int t = threadIdx.x;
  const int i4 = blockIdx.x * 32 + (t >> 3);  // v4 index over B*D/4 = 2048
  const int grp = t & 7;
  const int b = i4 >> 8, e4 = i4 & 255;
  const v4* p = (const v4*)partial + ((size_t)b << 8) + e4;
  v4 acc = {0.f, 0.f, 0.f, 0.f};
#pragma unroll
  for (int k = 0; k < 8; ++k)
    acc += p[(size_t)(grp + 8 * k) * (BATCH * 256)];
#pragma unroll
  for (int m = 4; m; m >>= 1) {
    acc.x += __shfl_xor(acc.x, m, 64);
    acc.y += __shfl_xor(acc.y, m, 64);
    acc.z += __shfl_xor(acc.z, m, 64);
    acc.w += __shfl_xor(acc.w, m, 64);
  }
  if (grp == 0) ((v4*)xsum)[i4] = acc;
}

// ---------------------------------------------------------------------------
// K3/K4: batched GEMV, wave per output (R1-proven shape).
// out[b,d] = sum_e in[b,e] * W[d,e] (+ bias[d]). grid 2048, block 256.
// ---------------------------------------------------------------------------
__global__ __launch_bounds__(256) void k_gemv(
    const float* __restrict__ vin, const float* __restrict__ W,
    const float* __restrict__ bias, float* __restrict__ vout) {
  const int wv = threadIdx.x >> 6, lane = threadIdx.x & 63;
  const int o = blockIdx.x * 4 + wv;   // 0 .. BATCH*DIM-1
  const int b = o >> 10, d = o & (DIM - 1);
  const v4* in4 = (const v4*)vin + ((size_t)b << 8);
  const v4* w4  = (const v4*)W + ((size_t)d << 8);
  float acc = 0.f;
#pragma unroll
  for (int j = 0; j < 4; ++j)
    acc += dot4(w4[lane + 64 * j], in4[lane + 64 * j]);
#pragma unroll
  for (int m = 32; m; m >>= 1) acc += __shfl_xor(acc, m, 64);
  if (lane == 0) {
    float r = acc;
    if (bias) r += bias[d];
    vout[o] = r;
  }
}

// ---------------------------------------------------------------------------
// K5: out[row,:] = LN(x[row,:] + z[b,:]) * gamma + beta.
// grid 1024 (16 rows/block), block 256 (4 waves x 4 rows).
// z/gamma/beta hoisted into per-lane register fragments once per block.
// ---------------------------------------------------------------------------
__global__ __launch_bounds__(256, 4) void k_residual_ln(
    const float* __restrict__ x, const float* __restrict__ z,
    const float* __restrict__ gamma, const float* __restrict__ beta,
    float* __restrict__ out) {
  __shared__ float zl[DIM];
  const int blk = blockIdx.x, t = threadIdx.x;
  const int wv = t >> 6, lane = t & 63;
  const int b = blk >> 7;   // 128 blocks per batch

  ((v4*)zl)[t] = ((const v4*)z)[((size_t)b << 8) + t];
  __syncthreads();

  v4 zf[4], gf[4], bf[4];
#pragma unroll
  for (int j = 0; j < 4; ++j) {
    zf[j] = ((const v4*)zl)[lane + 64 * j];
    gf[j] = ((const v4*)gamma)[lane + 64 * j];
    bf[j] = ((const v4*)beta)[lane + 64 * j];
  }

#pragma unroll 1
  for (int r = 0; r < 4; ++r) {
    const int row = (blk << 4) + (wv << 2) + r;
    const v4* xr = (const v4*)x + ((size_t)row << 8);
    v4 h[4];
    float sum = 0.f, ss = 0.f;
#pragma unroll
    for (int j = 0; j < 4; ++j) {
      v4 hv = xr[lane + 64 * j] + zf[j];
      h[j] = hv;
      sum += hv.x + hv.y + hv.z + hv.w;
      ss  += hv.x * hv.x + hv.y * hv.y + hv.z * hv.z + hv.w * hv.w;
    }
#pragma unroll
    for (int m = 32; m; m >>= 1) {
      sum += __shfl_xor(sum, m, 64);
      ss  += __shfl_xor(ss,  m, 64);
    }
    const float inv = 1.0f / (float)DIM;
    const float mu = sum * inv;
    const float rs = rsqrtf(ss * inv - mu * mu + LN_EPS);

    v4* outr = (v4*)out + ((size_t)row << 8);
#pragma unroll
    for (int j = 0; j < 4; ++j)
      outr[lane + 64 * j] = (h[j] - mu) * rs * gf[j] + bf[j];
  }
}

extern "C" void kernel_launch(void* const* d_in, const int* in_sizes, int n_in,
                              void* d_out, int out_size, void* d_ws, size_t ws_size,
                              hipStream_t stream) {
  const float* x     = (const float*)d_in[0];   // [B, S, D]
  const float* w_qkv = (const float*)d_in[1];   // [3D, D]
  const float* w_fc  = (const float*)d_in[2];   // [D, D]
  const float* b_fc  = (const float*)d_in[3];   // [D]
  const float* gamma = (const float*)d_in[4];   // [D]
  const float* beta  = (const float*)d_in[5];   // [D]
  float* out = (float*)d_out;

  // workspace layout (floats)
  float* partial = (float*)d_ws;                             // CHUNKS*B*D
  float* xsum    = partial + (size_t)CHUNKS * BATCH * DIM;   // B*D
  float* vsum    = xsum + (size_t)BATCH * DIM;               // B*D
  float* z       = vsum + (size_t)BATCH * DIM;               // B*D

  const float* w_v = w_qkv + (size_t)2 * DIM * DIM;  // rows [2D,3D) of w_qkv

  hipLaunchKernelGGL(k_partial_colsum, dim3(BATCH * CHUNKS), dim3(256), 0,
                     stream, x, partial);
  hipLaunchKernelGGL(k_finish_colsum, dim3(64), dim3(256), 0, stream,
                     partial, xsum);
  hipLaunchKernelGGL(k_gemv, dim3(BATCH * DIM / 4), dim3(256), 0, stream,
                     xsum, w_v, (const float*)nullptr, vsum);
  hipLaunchKernelGGL(k_gemv, dim3(BATCH * DIM / 4), dim3(256), 0, stream,
                     vsum, w_fc, b_fc, z);
  hipLaunchKernelGGL(k_residual_ln, dim3(BATCH * SEQ / 16), dim3(256), 0,
                     stream, x, z, gamma, beta, out);
}